// Round 16
// baseline (119.917 us; speedup 1.0000x reference)
//
#include <hip/hip_runtime.h>

typedef unsigned short u16b;
typedef __attribute__((ext_vector_type(4))) float f32x4;
typedef __attribute__((ext_vector_type(8))) short bf16x8;

#define GLD_LDS(g, l) __builtin_amdgcn_global_load_lds( \
    (__attribute__((address_space(1))) void*)(g), \
    (__attribute__((address_space(3))) void*)(l), 16, 0, 0)

__device__ __forceinline__ u16b f2bf(float f) {
    unsigned u = __builtin_bit_cast(unsigned, f);
    u += 0x7fffu + ((u >> 16) & 1u);
    return (u16b)(u >> 16);
}
__device__ __forceinline__ unsigned trunc_bf(float f) {   // truncating, for P only
    return __builtin_bit_cast(unsigned, f) >> 16;
}

// ---------------- fused prep: x cvt + w_attn^T cvt + w_proj^T cvt ----------------
__global__ void prep(const float* __restrict__ x, u16b* __restrict__ xb,
                     const float* __restrict__ w_attn, u16b* __restrict__ wab,
                     const float* __restrict__ w_proj, u16b* __restrict__ wpb) {
    __shared__ float tile[32][33];
    const int blk = blockIdx.x;
    if (blk < 4096) {
        int i = blk * 256 + threadIdx.x;
        float4 v = ((const float4*)x)[i];
        uint2 o;
        o.x = (unsigned)f2bf(v.x) | ((unsigned)f2bf(v.y) << 16);
        o.y = (unsigned)f2bf(v.z) | ((unsigned)f2bf(v.w) << 16);
        ((uint2*)xb)[i] = o;
        return;
    }
    const float* in;
    u16b* out;
    int idx, N;
    if (blk < 7168) { idx = blk - 4096; N = 3072; in = w_attn; out = wab; }
    else            { idx = blk - 7168; N = 1024; in = w_proj; out = wpb; }
    const int K = 1024;
    int kt = (idx & 31) * 32, nt = (idx >> 5) * 32;
    int c = threadIdx.x & 31, r8 = threadIdx.x >> 5;
    for (int i = 0; i < 4; i++) {
        int r = r8 + i * 8;
        tile[r][c] = in[(size_t)(kt + r) * N + nt + c];
    }
    __syncthreads();
    for (int i = 0; i < 4; i++) {
        int r = r8 + i * 8;
        out[(size_t)(nt + r) * K + kt + c] = f2bf(tile[c][r]);
    }
}

// ---------------- QKV GEMM: ring-3 counted-vmcnt pipeline ----------------
// BM=256 x BN=128, BK=64 (proven 128-byte-row swizzle), 512 thr = 8 waves (4M x 2N),
// wave tile 64x64 = the bit-proven 4x4-fragment geometry. 3 K-tile buffers (144 KB).
// Per tile t: STAGE(t+2) -> buf (t+2)%3 [its readers passed the end-of-(t-1) barrier
// before this issues: race-free by construction]; COMPUTE(t) from buf t%3;
// vmcnt(6) [leaves t+2's 6 loads/thread in flight, t+1 landed]; s_barrier.
// ONE barrier per K-tile, never vmcnt(0) mid-loop.
__global__ __launch_bounds__(512, 1) void gemm_ring_qkv(
    const u16b* __restrict__ A, const u16b* __restrict__ Bt,
    int M, int N, int K,
    const float* __restrict__ bias,
    float* __restrict__ out_f,
    u16b* __restrict__ q_ws, u16b* __restrict__ k_ws, u16b* __restrict__ v_t)
{
    __shared__ u16b sA[3][256 * 64];   // 32 KB per buffer
    __shared__ u16b sB[3][128 * 64];   // 16 KB per buffer
    const int tid = threadIdx.x;
    const int l = tid & 63, w = tid >> 6;          // w in [0,8)
    const int lr = l & 15, lg = l >> 4;
    const int m0 = blockIdx.y * 256, n0 = blockIdx.x * 128;
    const int wm = (w >> 1) * 64, wn = (w & 1) * 64;
    f32x4 acc[4][4] = {};

#define STAGE_R(t)                                                                \
    {                                                                             \
        const int _b = (t) % 3;                                                   \
        const int _kt = (t) << 6;                                                 \
        _Pragma("unroll")                                                         \
        for (int i = 0; i < 4; i++) {                                             \
            int chunk = i * 512 + tid;                                            \
            int row = chunk >> 3, cb = (chunk & 7) ^ (row & 7);                   \
            GLD_LDS(A + (size_t)(m0 + row) * K + _kt + cb * 8, &sA[_b][chunk * 8]); \
        }                                                                         \
        _Pragma("unroll")                                                         \
        for (int i = 0; i < 2; i++) {                                             \
            int chunk = i * 512 + tid;                                            \
            int row = chunk >> 3, cb = (chunk & 7) ^ (row & 7);                   \
            GLD_LDS(Bt + (size_t)(n0 + row) * K + _kt + cb * 8, &sB[_b][chunk * 8]); \
        }                                                                         \
    }

#define COMPUTE_R(t)                                                              \
    {                                                                             \
        const int _b = (t) % 3;                                                   \
        const char* pA = (const char*)&sA[_b][0];                                 \
        const char* pB = (const char*)&sB[_b][0];                                 \
        _Pragma("unroll")                                                         \
        for (int ks = 0; ks < 2; ks++) {                                          \
            bf16x8 af[4], bf[4];                                                  \
            _Pragma("unroll")                                                     \
            for (int i = 0; i < 4; i++) {                                         \
                int ar = wm + i * 16 + lr;                                        \
                af[i] = *(const bf16x8*)(pA + ar * 128 + ((ks * 64 + lg * 16) ^ ((ar & 7) << 4))); \
                int br = wn + i * 16 + lr;                                        \
                bf[i] = *(const bf16x8*)(pB + br * 128 + ((ks * 64 + lg * 16) ^ ((br & 7) << 4))); \
            }                                                                     \
            __builtin_amdgcn_s_setprio(1);                                        \
            _Pragma("unroll")                                                     \
            for (int mi = 0; mi < 4; mi++)                                        \
                _Pragma("unroll")                                                 \
                for (int ni = 0; ni < 4; ni++)                                    \
                    acc[mi][ni] = __builtin_amdgcn_mfma_f32_16x16x32_bf16(        \
                        af[mi], bf[ni], acc[mi][ni], 0, 0, 0);                    \
            __builtin_amdgcn_s_setprio(0);                                        \
        }                                                                         \
    }

    const int NT = K >> 6;   // 16 K-tiles
    STAGE_R(0);
    STAGE_R(1);
    asm volatile("s_waitcnt vmcnt(6)" ::: "memory");   // tile 0 landed (per wave)
    __builtin_amdgcn_s_barrier();                      // ... and globally

    #pragma unroll 1
    for (int t = 0; t < NT; ++t) {
        if (t + 2 < NT) STAGE_R(t + 2);
        COMPUTE_R(t);
        if (t + 1 < NT) {
            if (t + 2 < NT) asm volatile("s_waitcnt vmcnt(6)" ::: "memory");
            else            asm volatile("s_waitcnt vmcnt(0)" ::: "memory");
            __builtin_amdgcn_s_barrier();
        }
    }
#undef STAGE_R
#undef COMPUTE_R

    // QKV epilogue (proven): q/k bf16 ws, present fp32, V transposed into v_t
    const int qkv = n0 >> 10;
    #pragma unroll
    for (int ni = 0; ni < 4; ni++) {
        int n = n0 + wn + ni * 16 + lr;
        float bv = bias[n];
        int h = (n >> 6) & 15, d = n & 63;
        #pragma unroll
        for (int mi = 0; mi < 4; mi++) {
            const int mbase = m0 + wm + mi * 16 + lg * 4;
            const int b = mbase >> 11, tb = mbase & 2047;
            float cv[4];
            #pragma unroll
            for (int jj = 0; jj < 4; jj++)
                cv[jj] = acc[mi][ni][jj] + bv;
            if (qkv == 0) {
                #pragma unroll
                for (int jj = 0; jj < 4; jj++)
                    q_ws[((size_t)(b * 16 + h) * 2048 + tb + jj) * 64 + d] =
                        f2bf(cv[jj] * 0.18033688011f);   // 0.125 * log2(e)
            } else if (qkv == 1) {
                #pragma unroll
                for (int jj = 0; jj < 4; jj++) {
                    out_f[((size_t)((b * 2 + 0) * 16 + h) * 2048 + tb + jj) * 64 + d] = cv[jj];
                    k_ws[((size_t)(b * 16 + h) * 2048 + tb + jj) * 64 + d] = f2bf(cv[jj]);
                }
            } else {
                #pragma unroll
                for (int jj = 0; jj < 4; jj++)
                    out_f[((size_t)((b * 2 + 1) * 16 + h) * 2048 + tb + jj) * 64 + d] = cv[jj];
                uint2 pk;
                pk.x = (unsigned)f2bf(cv[0]) | ((unsigned)f2bf(cv[1]) << 16);
                pk.y = (unsigned)f2bf(cv[2]) | ((unsigned)f2bf(cv[3]) << 16);
                *(uint2*)(v_t + ((size_t)((b * 16 + h) * 64 + d)) * 2048 + tb) = pk;
            }
        }
    }
}

// ---------------- GEMM (projection): proven single-buffer 2-barrier template ----------------
template<int EPI, int MI, int NI>
__global__ __launch_bounds__(256, 2) void gemm_bt(
    const u16b* __restrict__ A, const u16b* __restrict__ Bt,
    int M, int N, int K,
    const float* __restrict__ bias,
    float* __restrict__ out_f)
{
    __shared__ u16b sA[(MI * 32) * 64];
    __shared__ u16b sB[(NI * 32) * 64];
    const int tid = threadIdx.x;
    const int l = tid & 63, w = tid >> 6;
    const int lr = l & 15, lg = l >> 4;
    const int m0 = blockIdx.y * (MI * 32), n0 = blockIdx.x * (NI * 32);
    const int wm = (w >> 1) * (MI * 16), wn = (w & 1) * (NI * 16);
    f32x4 acc[MI][NI] = {};

    for (int kt = 0; kt < K; kt += 64) {
        #pragma unroll
        for (int i = 0; i < MI; i++) {
            int chunk = i * 256 + tid;
            int row = chunk >> 3;
            int cb = (chunk & 7) ^ (row & 7);
            GLD_LDS(A + (size_t)(m0 + row) * K + kt + cb * 8, &sA[(i * 256 + w * 64) * 8]);
        }
        #pragma unroll
        for (int i = 0; i < NI; i++) {
            int chunk = i * 256 + tid;
            int row = chunk >> 3;
            int cb = (chunk & 7) ^ (row & 7);
            GLD_LDS(Bt + (size_t)(n0 + row) * K + kt + cb * 8, &sB[(i * 256 + w * 64) * 8]);
        }
        __syncthreads();
        #pragma unroll
        for (int ks = 0; ks < 2; ks++) {
            bf16x8 af[MI], bf[NI];
            #pragma unroll
            for (int i = 0; i < MI; i++) {
                int arow = wm + i * 16 + lr;
                af[i] = *(const bf16x8*)((const char*)sA + arow * 128 + ((ks * 64 + lg * 16) ^ ((arow & 7) << 4)));
            }
            #pragma unroll
            for (int i = 0; i < NI; i++) {
                int brow = wn + i * 16 + lr;
                bf[i] = *(const bf16x8*)((const char*)sB + brow * 128 + ((ks * 64 + lg * 16) ^ ((brow & 7) << 4)));
            }
            #pragma unroll
            for (int mi = 0; mi < MI; mi++)
                #pragma unroll
                for (int ni = 0; ni < NI; ni++)
                    acc[mi][ni] = __builtin_amdgcn_mfma_f32_16x16x32_bf16(af[mi], bf[ni], acc[mi][ni], 0, 0, 0);
        }
        __syncthreads();
    }

    #pragma unroll
    for (int ni = 0; ni < NI; ni++) {
        int col = n0 + wn + ni * 16 + lr;
        float bv = bias[col];
        #pragma unroll
        for (int mi = 0; mi < MI; mi++)
            #pragma unroll
            for (int jj = 0; jj < 4; jj++) {
                int rowm = m0 + wm + mi * 16 + lg * 4 + jj;
                out_f[(size_t)rowm * N + col] = acc[mi][ni][jj] + bv;
            }
    }
}

// ---------------- causal flash attention (R13-proven 4-wave dbuf version) ----------------
// grid 1024: bh = blk&31 (same-bh blocks 32 apart -> same XCD -> K/V L2-local).
// g = blk>>5 -> qt via balanced involution: co-resident CU groups {a,15-a,16+a,31-a}.
// Unnormalized softmax: P = exp2(S), L = sum P via ones-MFMA, divide once at end.
__global__ __launch_bounds__(256, 4) void attn_fwd(
    const u16b* __restrict__ q_ws, const u16b* __restrict__ k_ws,
    const u16b* __restrict__ v_t, u16b* __restrict__ a_ws)
{
    __shared__ u16b sK[2][64 * 64];   // [kv][d], XOR-swizzled
    __shared__ u16b sV[2][64 * 64];   // [d][kv], XOR-swizzled
    __shared__ u16b sP[4][16 * 64];   // per-wave [q][kv], XOR-swizzled
    const int tid = threadIdx.x;
    const int l = tid & 63, w = tid >> 6;
    const int lr = l & 15, lg = l >> 4;
    const int g = blockIdx.x >> 5, bh = blockIdx.x & 31;
    const int a = g & 7, bq = g >> 3;
    const int qt = (bq == 0) ? a : (bq == 1) ? 15 - a : (bq == 2) ? 16 + a : 31 - a;
    const int b = bh >> 4, h = bh & 15;
    const size_t kbase = (size_t)bh * 2048 * 64;
    const size_t vbase = (size_t)bh * 64 * 2048;

    const int chunk0 = tid, chunk1 = 256 + tid;
    const int row0 = chunk0 >> 3, cb0 = (chunk0 & 7) ^ (row0 & 7);
    const int row1 = chunk1 >> 3, cb1 = (chunk1 & 7) ^ (row1 & 7);
    const u16b* kp0 = k_ws + kbase + (size_t)row0 * 64 + cb0 * 8;
    const u16b* kp1 = k_ws + kbase + (size_t)row1 * 64 + cb1 * 8;
    const u16b* vp0 = v_t + vbase + (size_t)row0 * 2048 + cb0 * 8;
    const u16b* vp1 = v_t + vbase + (size_t)row1 * 2048 + cb1 * 8;

    bf16x8 qf[2];
    {
        const u16b* qp = q_ws + kbase + (size_t)(qt * 64 + w * 16 + lr) * 64 + lg * 8;
        qf[0] = *(const bf16x8*)qp;
        qf[1] = *(const bf16x8*)(qp + 32);
    }
    const bf16x8 ones = {0x3F80, 0x3F80, 0x3F80, 0x3F80, 0x3F80, 0x3F80, 0x3F80, 0x3F80};
    f32x4 Oacc[4] = {};
    f32x4 Lacc = {};                  // row-sum in jj-layout (via ones-MFMA)

    GLD_LDS(kp0, &sK[0][chunk0 * 8]);
    GLD_LDS(kp1, &sK[0][chunk1 * 8]);
    GLD_LDS(vp0, &sV[0][chunk0 * 8]);
    GLD_LDS(vp1, &sV[0][chunk1 * 8]);
    __syncthreads();
    int cur = 0;

    #pragma unroll 1
    for (int j = 0; j <= qt; j++) {
        if (j < qt) {
            int nxt = cur ^ 1;
            size_t ko = (size_t)(j + 1) * 64 * 64;
            size_t vo = (size_t)(j + 1) * 64;
            GLD_LDS(kp0 + ko, &sK[nxt][chunk0 * 8]);
            GLD_LDS(kp1 + ko, &sK[nxt][chunk1 * 8]);
            GLD_LDS(vp0 + vo, &sV[nxt][chunk0 * 8]);
            GLD_LDS(vp1 + vo, &sV[nxt][chunk1 * 8]);
        }
        const u16b* cK = &sK[cur][0];
        const u16b* cV = &sV[cur][0];

        // S^T = K Q^T : lane (lr,lg) holds S[q=w*16+lr][kv=c*16+lg*4+jj]
        f32x4 S[4];
        __builtin_amdgcn_s_setprio(1);
        #pragma unroll
        for (int c = 0; c < 4; c++) {
            f32x4 s = {};
            #pragma unroll
            for (int ks = 0; ks < 2; ks++) {
                int krow = c * 16 + lr;
                bf16x8 kf = *(const bf16x8*)((const char*)cK + krow * 128 + ((ks * 64 + lg * 16) ^ ((krow & 7) << 4)));
                s = __builtin_amdgcn_mfma_f32_16x16x32_bf16(kf, qf[ks], s, 0, 0, 0);
            }
            S[c] = s;
        }
        __builtin_amdgcn_s_setprio(0);
        if (j == qt) {
            const int ql = w * 16 + lr;
            #pragma unroll
            for (int c = 0; c < 4; c++)
                #pragma unroll
                for (int jj = 0; jj < 4; jj++)
                    if (c * 16 + lg * 4 + jj > ql) S[c][jj] = -1e9f;
        }
        // P = exp2(S) unnormalized; pack to bf16, write to per-wave LDS
        u16b* myP = &sP[w][0];
        #pragma unroll
        for (int c = 0; c < 4; c++) {
            #pragma unroll
            for (int jj = 0; jj < 4; jj++)
                S[c][jj] = __builtin_amdgcn_exp2f(S[c][jj]);
            uint2 pk;
            pk.x = trunc_bf(S[c][0]) | (trunc_bf(S[c][1]) << 16);
            pk.y = trunc_bf(S[c][2]) | (trunc_bf(S[c][3]) << 16);
            *(uint2*)((char*)myP + lr * 128 + ((c * 32 + lg * 8) ^ ((lr & 7) << 4))) = pk;
        }
        // O += P V ; L += P * ones  (row-sum, jj-layout)
        __builtin_amdgcn_s_setprio(1);
        #pragma unroll
        for (int ks = 0; ks < 2; ks++) {
            bf16x8 pa = *(const bf16x8*)((const char*)myP + lr * 128 + ((ks * 64 + lg * 16) ^ ((lr & 7) << 4)));
            #pragma unroll
            for (int dc = 0; dc < 4; dc++) {
                int vrow = dc * 16 + lr;
                bf16x8 vb = *(const bf16x8*)((const char*)cV + vrow * 128 + ((ks * 64 + lg * 16) ^ ((vrow & 7) << 4)));
                Oacc[dc] = __builtin_amdgcn_mfma_f32_16x16x32_bf16(pa, vb, Oacc[dc], 0, 0, 0);
            }
            Lacc = __builtin_amdgcn_mfma_f32_16x16x32_bf16(pa, ones, Lacc, 0, 0, 0);
        }
        __builtin_amdgcn_s_setprio(0);
        __syncthreads();
        cur ^= 1;
    }
    // epilogue: all lane-local (Lacc jj-layout matches Oacc)
    #pragma unroll
    for (int jj = 0; jj < 4; jj++) {
        float inv = 1.f / Lacc[jj];
        int q = qt * 64 + w * 16 + lg * 4 + jj;
        #pragma unroll
        for (int dc = 0; dc < 4; dc++) {
            int d = dc * 16 + lr;
            a_ws[(size_t)(b * 2048 + q) * 1024 + h * 64 + d] = f2bf(Oacc[dc][jj] * inv);
        }
    }
}

extern "C" void kernel_launch(void* const* d_in, const int* in_sizes, int n_in,
                              void* d_out, int out_size, void* d_ws, size_t ws_size,
                              hipStream_t stream) {
    const float* x      = (const float*)d_in[0];
    const float* w_attn = (const float*)d_in[1];
    const float* b_attn = (const float*)d_in[2];
    const float* w_proj = (const float*)d_in[3];
    const float* b_proj = (const float*)d_in[4];
    float* out = (float*)d_out;
    float* present = out + 4194304;

    char* ws = (char*)d_ws;
    u16b* xb   = (u16b*)(ws);                // [4096][1024]
    u16b* wab  = (u16b*)(ws + 8388608);      // [3072][1024]
    u16b* wpb  = (u16b*)(ws + 14680064);     // [1024][1024]
    u16b* q_ws = (u16b*)(ws + 16777216);     // [B,H,T,64] (pre-scaled, exp2 domain)
    u16b* k_ws = (u16b*)(ws + 25165824);     // [B,H,T,64]
    u16b* v_t  = (u16b*)(ws + 33554432);     // [B,H,64,T]  (transposed V, by gemm0)
    u16b* a_ws = (u16b*)(ws + 41943040);     // [4096][1024]

    prep<<<8192, 256, 0, stream>>>(x, xb, w_attn, wab, w_proj, wpb);
    gemm_ring_qkv<<<dim3(24, 16), 512, 0, stream>>>(xb, wab, 4096, 3072, 1024, b_attn,
                                                    present, q_ws, k_ws, v_t);
    attn_fwd<<<1024, 256, 0, stream>>>(q_ws, k_ws, v_t, a_ws);
    gemm_bt<1, 2, 2><<<dim3(16, 64), 256, 0, stream>>>(a_ws, wpb, 4096, 1024, 1024, b_proj,
                                                       out);
}

// Round 17
// 100.394 us; speedup vs baseline: 1.1945x; 1.1945x over previous
//
#include <hip/hip_runtime.h>

typedef unsigned short u16b;
typedef __attribute__((ext_vector_type(4))) float f32x4;
typedef __attribute__((ext_vector_type(8))) short bf16x8;

#define GLD_LDS(g, l) __builtin_amdgcn_global_load_lds( \
    (__attribute__((address_space(1))) void*)(g), \
    (__attribute__((address_space(3))) void*)(l), 16, 0, 0)

__device__ __forceinline__ u16b f2bf(float f) {
    unsigned u = __builtin_bit_cast(unsigned, f);
    u += 0x7fffu + ((u >> 16) & 1u);
    return (u16b)(u >> 16);
}
__device__ __forceinline__ unsigned trunc_bf(float f) {   // truncating, for P only
    return __builtin_bit_cast(unsigned, f) >> 16;
}

// ---------------- fused prep: x cvt + w_attn^T cvt + w_proj^T cvt ----------------
__global__ void prep(const float* __restrict__ x, u16b* __restrict__ xb,
                     const float* __restrict__ w_attn, u16b* __restrict__ wab,
                     const float* __restrict__ w_proj, u16b* __restrict__ wpb) {
    __shared__ float tile[32][33];
    const int blk = blockIdx.x;
    if (blk < 4096) {
        int i = blk * 256 + threadIdx.x;
        float4 v = ((const float4*)x)[i];
        uint2 o;
        o.x = (unsigned)f2bf(v.x) | ((unsigned)f2bf(v.y) << 16);
        o.y = (unsigned)f2bf(v.z) | ((unsigned)f2bf(v.w) << 16);
        ((uint2*)xb)[i] = o;
        return;
    }
    const float* in;
    u16b* out;
    int idx, N;
    if (blk < 7168) { idx = blk - 4096; N = 3072; in = w_attn; out = wab; }
    else            { idx = blk - 7168; N = 1024; in = w_proj; out = wpb; }
    const int K = 1024;
    int kt = (idx & 31) * 32, nt = (idx >> 5) * 32;
    int c = threadIdx.x & 31, r8 = threadIdx.x >> 5;
    for (int i = 0; i < 4; i++) {
        int r = r8 + i * 8;
        tile[r][c] = in[(size_t)(kt + r) * N + nt + c];
    }
    __syncthreads();
    for (int i = 0; i < 4; i++) {
        int r = r8 + i * 8;
        out[(size_t)(nt + r) * K + kt + c] = f2bf(tile[c][r]);
    }
}

// ---------------- GEMM: C[M][N] = A[M][K] * Bt[N][K]^T  (bf16 in, fp32 acc) ----------------
// PROVEN single-buffer 2-barrier structure (42.2us on QKV shape; structure ceiling).
// EPI=0 (QKV): q/k bf16 ws, present fp32, V transposed directly into v_t [bh][d][t].
template<int EPI, int MI, int NI>
__global__ __launch_bounds__(256, 2) void gemm_bt(
    const u16b* __restrict__ A, const u16b* __restrict__ Bt,
    int M, int N, int K,
    const float* __restrict__ bias,
    float* __restrict__ out_f,
    u16b* __restrict__ q_ws, u16b* __restrict__ k_ws, u16b* __restrict__ v_t)
{
    __shared__ u16b sA[(MI * 32) * 64];
    __shared__ u16b sB[(NI * 32) * 64];
    const int tid = threadIdx.x;
    const int l = tid & 63, w = tid >> 6;
    const int lr = l & 15, lg = l >> 4;
    const int m0 = blockIdx.y * (MI * 32), n0 = blockIdx.x * (NI * 32);
    const int wm = (w >> 1) * (MI * 16), wn = (w & 1) * (NI * 16);
    f32x4 acc[MI][NI] = {};

    for (int kt = 0; kt < K; kt += 64) {
        #pragma unroll
        for (int i = 0; i < MI; i++) {
            int chunk = i * 256 + tid;
            int row = chunk >> 3;
            int cb = (chunk & 7) ^ (row & 7);
            GLD_LDS(A + (size_t)(m0 + row) * K + kt + cb * 8, &sA[(i * 256 + w * 64) * 8]);
        }
        #pragma unroll
        for (int i = 0; i < NI; i++) {
            int chunk = i * 256 + tid;
            int row = chunk >> 3;
            int cb = (chunk & 7) ^ (row & 7);
            GLD_LDS(Bt + (size_t)(n0 + row) * K + kt + cb * 8, &sB[(i * 256 + w * 64) * 8]);
        }
        __syncthreads();
        #pragma unroll
        for (int ks = 0; ks < 2; ks++) {
            bf16x8 af[MI], bf[NI];
            #pragma unroll
            for (int i = 0; i < MI; i++) {
                int arow = wm + i * 16 + lr;
                af[i] = *(const bf16x8*)((const char*)sA + arow * 128 + ((ks * 64 + lg * 16) ^ ((arow & 7) << 4)));
            }
            #pragma unroll
            for (int i = 0; i < NI; i++) {
                int brow = wn + i * 16 + lr;
                bf[i] = *(const bf16x8*)((const char*)sB + brow * 128 + ((ks * 64 + lg * 16) ^ ((brow & 7) << 4)));
            }
            #pragma unroll
            for (int mi = 0; mi < MI; mi++)
                #pragma unroll
                for (int ni = 0; ni < NI; ni++)
                    acc[mi][ni] = __builtin_amdgcn_mfma_f32_16x16x32_bf16(af[mi], bf[ni], acc[mi][ni], 0, 0, 0);
        }
        __syncthreads();
    }

    if (EPI == 1) {
        #pragma unroll
        for (int ni = 0; ni < NI; ni++) {
            int col = n0 + wn + ni * 16 + lr;
            float bv = bias[col];
            #pragma unroll
            for (int mi = 0; mi < MI; mi++)
                #pragma unroll
                for (int jj = 0; jj < 4; jj++) {
                    int rowm = m0 + wm + mi * 16 + lg * 4 + jj;
                    out_f[(size_t)rowm * N + col] = acc[mi][ni][jj] + bv;
                }
        }
    } else {
        const int qkv = n0 >> 10;
        #pragma unroll
        for (int ni = 0; ni < NI; ni++) {
            int n = n0 + wn + ni * 16 + lr;
            float bv = bias[n];
            int h = (n >> 6) & 15, d = n & 63;
            #pragma unroll
            for (int mi = 0; mi < MI; mi++) {
                const int mbase = m0 + wm + mi * 16 + lg * 4;   // jj=0..3 -> consecutive m
                const int b = mbase >> 11, tb = mbase & 2047;   // same b for all jj
                float cv[4];
                #pragma unroll
                for (int jj = 0; jj < 4; jj++)
                    cv[jj] = acc[mi][ni][jj] + bv;
                if (qkv == 0) {
                    #pragma unroll
                    for (int jj = 0; jj < 4; jj++)
                        q_ws[((size_t)(b * 16 + h) * 2048 + tb + jj) * 64 + d] =
                            f2bf(cv[jj] * 0.18033688011f);   // 0.125 * log2(e)
                } else if (qkv == 1) {
                    #pragma unroll
                    for (int jj = 0; jj < 4; jj++) {
                        out_f[((size_t)((b * 2 + 0) * 16 + h) * 2048 + tb + jj) * 64 + d] = cv[jj];
                        k_ws[((size_t)(b * 16 + h) * 2048 + tb + jj) * 64 + d] = f2bf(cv[jj]);
                    }
                } else {
                    #pragma unroll
                    for (int jj = 0; jj < 4; jj++)
                        out_f[((size_t)((b * 2 + 1) * 16 + h) * 2048 + tb + jj) * 64 + d] = cv[jj];
                    uint2 pk;
                    pk.x = (unsigned)f2bf(cv[0]) | ((unsigned)f2bf(cv[1]) << 16);
                    pk.y = (unsigned)f2bf(cv[2]) | ((unsigned)f2bf(cv[3]) << 16);
                    *(uint2*)(v_t + ((size_t)((b * 16 + h) * 64 + d)) * 2048 + tb) = pk;
                }
            }
        }
    }
}

// ---------------- causal flash attention (proven 4-wave dbuf version) ----------------
// grid 1024: bh = blk&31 (same-bh blocks 32 apart -> same XCD -> K/V L2-local).
// g = blk>>5 -> qt via balanced involution: co-resident CU groups {a,15-a,16+a,31-a}.
// Unnormalized softmax: P = exp2(S), L = sum P via ones-MFMA, divide once at end.
__global__ __launch_bounds__(256, 4) void attn_fwd(
    const u16b* __restrict__ q_ws, const u16b* __restrict__ k_ws,
    const u16b* __restrict__ v_t, u16b* __restrict__ a_ws)
{
    __shared__ u16b sK[2][64 * 64];   // [kv][d], XOR-swizzled
    __shared__ u16b sV[2][64 * 64];   // [d][kv], XOR-swizzled
    __shared__ u16b sP[4][16 * 64];   // per-wave [q][kv], XOR-swizzled
    const int tid = threadIdx.x;
    const int l = tid & 63, w = tid >> 6;
    const int lr = l & 15, lg = l >> 4;
    const int g = blockIdx.x >> 5, bh = blockIdx.x & 31;
    const int a = g & 7, bq = g >> 3;
    const int qt = (bq == 0) ? a : (bq == 1) ? 15 - a : (bq == 2) ? 16 + a : 31 - a;
    const int b = bh >> 4, h = bh & 15;
    const size_t kbase = (size_t)bh * 2048 * 64;
    const size_t vbase = (size_t)bh * 64 * 2048;

    const int chunk0 = tid, chunk1 = 256 + tid;
    const int row0 = chunk0 >> 3, cb0 = (chunk0 & 7) ^ (row0 & 7);
    const int row1 = chunk1 >> 3, cb1 = (chunk1 & 7) ^ (row1 & 7);
    const u16b* kp0 = k_ws + kbase + (size_t)row0 * 64 + cb0 * 8;
    const u16b* kp1 = k_ws + kbase + (size_t)row1 * 64 + cb1 * 8;
    const u16b* vp0 = v_t + vbase + (size_t)row0 * 2048 + cb0 * 8;
    const u16b* vp1 = v_t + vbase + (size_t)row1 * 2048 + cb1 * 8;

    bf16x8 qf[2];
    {
        const u16b* qp = q_ws + kbase + (size_t)(qt * 64 + w * 16 + lr) * 64 + lg * 8;
        qf[0] = *(const bf16x8*)qp;
        qf[1] = *(const bf16x8*)(qp + 32);
    }
    const bf16x8 ones = {0x3F80, 0x3F80, 0x3F80, 0x3F80, 0x3F80, 0x3F80, 0x3F80, 0x3F80};
    f32x4 Oacc[4] = {};
    f32x4 Lacc = {};                  // row-sum in jj-layout (via ones-MFMA)

    GLD_LDS(kp0, &sK[0][chunk0 * 8]);
    GLD_LDS(kp1, &sK[0][chunk1 * 8]);
    GLD_LDS(vp0, &sV[0][chunk0 * 8]);
    GLD_LDS(vp1, &sV[0][chunk1 * 8]);
    __syncthreads();
    int cur = 0;

    #pragma unroll 1
    for (int j = 0; j <= qt; j++) {
        if (j < qt) {
            int nxt = cur ^ 1;
            size_t ko = (size_t)(j + 1) * 64 * 64;
            size_t vo = (size_t)(j + 1) * 64;
            GLD_LDS(kp0 + ko, &sK[nxt][chunk0 * 8]);
            GLD_LDS(kp1 + ko, &sK[nxt][chunk1 * 8]);
            GLD_LDS(vp0 + vo, &sV[nxt][chunk0 * 8]);
            GLD_LDS(vp1 + vo, &sV[nxt][chunk1 * 8]);
        }
        const u16b* cK = &sK[cur][0];
        const u16b* cV = &sV[cur][0];

        // S^T = K Q^T : lane (lr,lg) holds S[q=w*16+lr][kv=c*16+lg*4+jj]
        f32x4 S[4];
        __builtin_amdgcn_s_setprio(1);
        #pragma unroll
        for (int c = 0; c < 4; c++) {
            f32x4 s = {};
            #pragma unroll
            for (int ks = 0; ks < 2; ks++) {
                int krow = c * 16 + lr;
                bf16x8 kf = *(const bf16x8*)((const char*)cK + krow * 128 + ((ks * 64 + lg * 16) ^ ((krow & 7) << 4)));
                s = __builtin_amdgcn_mfma_f32_16x16x32_bf16(kf, qf[ks], s, 0, 0, 0);
            }
            S[c] = s;
        }
        __builtin_amdgcn_s_setprio(0);
        if (j == qt) {
            const int ql = w * 16 + lr;
            #pragma unroll
            for (int c = 0; c < 4; c++)
                #pragma unroll
                for (int jj = 0; jj < 4; jj++)
                    if (c * 16 + lg * 4 + jj > ql) S[c][jj] = -1e9f;
        }
        // P = exp2(S) unnormalized; pack to bf16, write to per-wave LDS
        u16b* myP = &sP[w][0];
        #pragma unroll
        for (int c = 0; c < 4; c++) {
            #pragma unroll
            for (int jj = 0; jj < 4; jj++)
                S[c][jj] = __builtin_amdgcn_exp2f(S[c][jj]);
            uint2 pk;
            pk.x = trunc_bf(S[c][0]) | (trunc_bf(S[c][1]) << 16);
            pk.y = trunc_bf(S[c][2]) | (trunc_bf(S[c][3]) << 16);
            *(uint2*)((char*)myP + lr * 128 + ((c * 32 + lg * 8) ^ ((lr & 7) << 4))) = pk;
        }
        // O += P V ; L += P * ones  (row-sum, jj-layout)
        __builtin_amdgcn_s_setprio(1);
        #pragma unroll
        for (int ks = 0; ks < 2; ks++) {
            bf16x8 pa = *(const bf16x8*)((const char*)myP + lr * 128 + ((ks * 64 + lg * 16) ^ ((lr & 7) << 4)));
            #pragma unroll
            for (int dc = 0; dc < 4; dc++) {
                int vrow = dc * 16 + lr;
                bf16x8 vb = *(const bf16x8*)((const char*)cV + vrow * 128 + ((ks * 64 + lg * 16) ^ ((vrow & 7) << 4)));
                Oacc[dc] = __builtin_amdgcn_mfma_f32_16x16x32_bf16(pa, vb, Oacc[dc], 0, 0, 0);
            }
            Lacc = __builtin_amdgcn_mfma_f32_16x16x32_bf16(pa, ones, Lacc, 0, 0, 0);
        }
        __builtin_amdgcn_s_setprio(0);
        __syncthreads();
        cur ^= 1;
    }
    // epilogue: all lane-local (Lacc jj-layout matches Oacc)
    #pragma unroll
    for (int jj = 0; jj < 4; jj++) {
        float inv = 1.f / Lacc[jj];
        int q = qt * 64 + w * 16 + lg * 4 + jj;
        #pragma unroll
        for (int dc = 0; dc < 4; dc++) {
            int d = dc * 16 + lr;
            a_ws[(size_t)(b * 2048 + q) * 1024 + h * 64 + d] = f2bf(Oacc[dc][jj] * inv);
        }
    }
}

extern "C" void kernel_launch(void* const* d_in, const int* in_sizes, int n_in,
                              void* d_out, int out_size, void* d_ws, size_t ws_size,
                              hipStream_t stream) {
    const float* x      = (const float*)d_in[0];
    const float* w_attn = (const float*)d_in[1];
    const float* b_attn = (const float*)d_in[2];
    const float* w_proj = (const float*)d_in[3];
    const float* b_proj = (const float*)d_in[4];
    float* out = (float*)d_out;
    float* present = out + 4194304;

    char* ws = (char*)d_ws;
    u16b* xb   = (u16b*)(ws);                // [4096][1024]
    u16b* wab  = (u16b*)(ws + 8388608);      // [3072][1024]
    u16b* wpb  = (u16b*)(ws + 14680064);     // [1024][1024]
    u16b* q_ws = (u16b*)(ws + 16777216);     // [B,H,T,64] (pre-scaled, exp2 domain)
    u16b* k_ws = (u16b*)(ws + 25165824);     // [B,H,T,64]
    u16b* v_t  = (u16b*)(ws + 33554432);     // [B,H,64,T]  (transposed V, by gemm0)
    u16b* a_ws = (u16b*)(ws + 41943040);     // [4096][1024]

    prep<<<8192, 256, 0, stream>>>(x, xb, w_attn, wab, w_proj, wpb);
    gemm_bt<0, 4, 4><<<dim3(24, 32), 256, 0, stream>>>(xb, wab, 4096, 3072, 1024, b_attn,
                                                       present, q_ws, k_ws, v_t);
    attn_fwd<<<1024, 256, 0, stream>>>(q_ws, k_ws, v_t, a_ws);
    gemm_bt<1, 2, 2><<<dim3(16, 64), 256, 0, stream>>>(a_ws, wpb, 4096, 1024, 1024, b_proj,
                                                       out, nullptr, nullptr, nullptr);
}